// Round 3
// baseline (1110.820 us; speedup 1.0000x reference)
//
#include <hip/hip_runtime.h>

// Counting-sort + LDS accumulation (no global atomics in main path).
// R6 -> R7: R6's two-pass never ran (414 MB > ~256 MB ws; fallback took over,
// dur unchanged). Cost model: every SCATTERED vmem op ~10 cy/CU regardless of
// MLP (R4==R5==R6): k_accum = 25.6M random gathers (556us), k_scatter = 25.6M
// scattered stores (~390us hidden). Fix BOTH within ws:
//   - triangular (bucket-pair) sort: ONE 8B tuple per edge (12.8M scattered
//     stores, half of before; tuples = 102 MB, total ws ~155 MB).
//   - kc_accum: block row R stages bucket q charges in LDS (prefetched),
//     off-diag tiles visited twice (stream re-read is cheap), diag applies
//     both directions. Zero random gathers. LDS 64 KB = 2 blocks/CU.

#define BLOCK   256
#define NBLK    1024
#define NBLK_LG 10
#define AB_LOG  10
#define A_B     1024
#define PLANE   1056
#define MAXNB   256

// ---- composite (triangular) sort params ----
#define NCHUNK   512        // edge chunks for kc_hist / kc_scatter
#define BLK_SORT 1024
#define AB2_LOG  11
#define A_B2     2048       // atoms per bucket (both roles)
#define MAXBINS  10240      // LDS hist/cur capacity (40 KB)
#define QS_PER   14         // q-buckets per kc_accum slice

static __device__ __forceinline__ unsigned long long nt_u64(const void* p) {
    return __builtin_nontemporal_load((const unsigned long long*)p);
}
static __device__ __forceinline__ float nt_f32(const float* p) {
    return __builtin_nontemporal_load(p);
}
typedef float v4f __attribute__((ext_vector_type(4)));
static __device__ __forceinline__ void nt_store_f4(float4 v, float4* p) {
    v4f x; x.x = v.x; x.y = v.y; x.z = v.z; x.w = v.w;
    __builtin_nontemporal_store(x, (v4f*)p);
}
static __device__ __forceinline__ int tri_bin(int P, int Q, int nb2) {
    // P <= Q; triangular index
    return P * nb2 - ((P * (P - 1)) >> 1) + (Q - P);
}

// ======================= triangular-sort pipeline ========================

// ---- KC1: per-chunk histogram over triangular bins ----------------------
__global__ __launch_bounds__(BLK_SORT) void kc_hist(
    const int2* __restrict__ nbr, int* __restrict__ chist,
    int n_edges, int nb2, int nbins)
{
    __shared__ int h[MAXBINS];
    for (int i = threadIdx.x; i < nbins; i += BLK_SORT) h[i] = 0;
    __syncthreads();
    int per = (n_edges + NCHUNK - 1) / NCHUNK;
    int lo = blockIdx.x * per;
    int hi = min(lo + per, n_edges);
    #pragma unroll 2
    for (int e = lo + threadIdx.x; e < hi; e += BLK_SORT) {
        unsigned long long v = nt_u64(&nbr[e]);
        int ix = (int)(v & 0xffffffffu);
        int iy = (int)(v >> 32);
        int bx = ix >> AB2_LOG, by = iy >> AB2_LOG;
        int P = min(bx, by), Q = max(bx, by);
        atomicAdd(&h[tri_bin(P, Q, nb2)], 1);
    }
    __syncthreads();
    // chunk-major: contiguous 4*nbins write per block
    int* out = chist + (size_t)blockIdx.x * nbins;
    for (int i = threadIdx.x; i < nbins; i += BLK_SORT) out[i] = h[i];
}

// ---- KC2: scan each bin's NCHUNK entries --------------------------------
__global__ __launch_bounds__(NCHUNK) void kc_rowscan(
    const int* __restrict__ chist, int* __restrict__ coffs,
    int* __restrict__ ctot, int nbins)
{
    __shared__ int a[NCHUNK];
    int bin = blockIdx.x, t = threadIdx.x;
    int v = chist[(size_t)t * nbins + bin];
    a[t] = v;
    __syncthreads();
    for (int off = 1; off < NCHUNK; off <<= 1) {
        int x = (t >= off) ? a[t - off] : 0;
        __syncthreads();
        a[t] += x;
        __syncthreads();
    }
    coffs[(size_t)t * nbins + bin] = a[t] - v;
    if (t == NCHUNK - 1) ctot[bin] = a[t];
}

// ---- KC3: exclusive scan of bin totals (one block) ----------------------
__global__ __launch_bounds__(1024) void kc_bases(
    const int* __restrict__ ctot, int* __restrict__ cbase, int nbins)
{
    __shared__ int sums[1024];
    int t = threadIdx.x;
    int items = (nbins + 1023) >> 10;    // <= 10 for MAXBINS
    int v[16];
    int run = 0;
    #pragma unroll
    for (int k = 0; k < 16; ++k) {
        if (k < items) {
            int idx = t * items + k;
            int x = (idx < nbins) ? ctot[idx] : 0;
            v[k] = run; run += x;
        }
    }
    sums[t] = run;
    __syncthreads();
    for (int off = 1; off < 1024; off <<= 1) {
        int x = (t >= off) ? sums[t - off] : 0;
        __syncthreads();
        sums[t] += x;
        __syncthreads();
    }
    int prefix = (t == 0) ? 0 : sums[t - 1];
    #pragma unroll
    for (int k = 0; k < 16; ++k) {
        if (k < items) {
            int idx = t * items + k;
            if (idx < nbins) cbase[idx] = prefix + v[k];
        }
    }
}

// ---- KC4: coffs[c][bin] += cbase[bin] -----------------------------------
__global__ __launch_bounds__(1024) void kc_addbase(
    int* __restrict__ coffs, const int* __restrict__ cbase, int nbins)
{
    int bin = blockIdx.x * 1024 + threadIdx.x;
    if (bin < nbins)
        coffs[(size_t)blockIdx.y * nbins + bin] += cbase[bin];
}

// ---- KC5: scatter ONE tuple per edge into triangular bins ---------------
// tuple.x = loLocal(11) | hiLocal(11)<<11 ; tuple.y = w bits
__global__ __launch_bounds__(BLK_SORT) void kc_scatter(
    const int2* __restrict__ nbr, const float* __restrict__ dist,
    const int* __restrict__ coffs, uint2* __restrict__ tuples,
    int n_edges, int nb2, int nbins)
{
    __shared__ int cur[MAXBINS];
    const int* src = coffs + (size_t)blockIdx.x * nbins;
    for (int i = threadIdx.x; i < nbins; i += BLK_SORT) cur[i] = src[i];
    __syncthreads();
    int per = (n_edges + NCHUNK - 1) / NCHUNK;
    int lo = blockIdx.x * per;
    int hi = min(lo + per, n_edges);
    #pragma unroll 2
    for (int e = lo + threadIdx.x; e < hi; e += BLK_SORT) {
        unsigned long long v = nt_u64(&nbr[e]);
        int ix = (int)(v & 0xffffffffu);
        int iy = (int)(v >> 32);
        float w = 0.5f / nt_f32(&dist[e]);
        int bx = ix >> AB2_LOG, by = iy >> AB2_LOG;
        int a, b;
        if (bx <= by) { a = ix; b = iy; } else { a = iy; b = ix; }
        int P = min(bx, by), Q = max(bx, by);
        int bin = tri_bin(P, Q, nb2);
        int pos = atomicAdd(&cur[bin], 1);
        tuples[pos] = make_uint2(
            (unsigned)(a & (A_B2 - 1)) | ((unsigned)(b & (A_B2 - 1)) << AB2_LOG),
            __float_as_uint(w));
    }
}

// ---- KC6: row-R accumulation; stage bucket q in LDS, no gathers ---------
__global__ __launch_bounds__(BLK_SORT) void kc_accum(
    const uint2* __restrict__ tuples, const float4* __restrict__ charges,
    const int* __restrict__ cbase, const int* __restrict__ ctot,
    float4* __restrict__ partials, int nb2, int nsl, int n_atoms)
{
    __shared__ float  acc[4 * A_B2];   // 32 KB, plane-major
    __shared__ float4 stg[A_B2];       // 32 KB staged charges of bucket q
    int R  = blockIdx.x / nsl;
    int sl = blockIdx.x % nsl;
    int tid = threadIdx.x;
    for (int i = tid; i < 4 * A_B2; i += BLK_SORT) acc[i] = 0.f;
    int q0 = sl * QS_PER;
    int q1 = min(q0 + QS_PER, nb2);
    float4 z = make_float4(0.f, 0.f, 0.f, 0.f);
    {   // stage bucket q0
        int abase = q0 << AB2_LOG, lim = n_atoms - abase;
        stg[tid]            = (tid < lim)            ? charges[abase + tid]            : z;
        stg[tid + BLK_SORT] = (tid + BLK_SORT < lim) ? charges[abase + tid + BLK_SORT] : z;
    }
    __syncthreads();

    for (int q = q0; q < q1; ++q) {
        float4 pre0, pre1;
        bool more = (q + 1 < q1);
        if (more) {   // T14 split: issue next-bucket loads now, write later
            int abase = (q + 1) << AB2_LOG, lim = n_atoms - abase;
            pre0 = (tid < lim)            ? charges[abase + tid]            : z;
            pre1 = (tid + BLK_SORT < lim) ? charges[abase + tid + BLK_SORT] : z;
        }
        int P = min(R, q), Q = max(R, q);
        int bin = tri_bin(P, Q, nb2);
        int lo = cbase[bin], hi = lo + ctot[bin];
        if (q == R) {
            // diagonal: apply both directions in one visit
            for (int p = lo + tid; p < hi; p += BLK_SORT) {
                unsigned long long t = nt_u64(&tuples[p]);
                unsigned x = (unsigned)t;
                float w = __uint_as_float((unsigned)(t >> 32));
                int l = (int)(x & (A_B2 - 1));
                int h = (int)((x >> AB2_LOG) & (A_B2 - 1));
                float4 cl = stg[l];
                float4 ch = stg[h];
                atomicAdd(&acc[l],             ch.x * w);
                atomicAdd(&acc[A_B2 + l],      ch.y * w);
                atomicAdd(&acc[2 * A_B2 + l],  ch.z * w);
                atomicAdd(&acc[3 * A_B2 + l],  ch.w * w);
                atomicAdd(&acc[h],             cl.x * w);
                atomicAdd(&acc[A_B2 + h],      cl.y * w);
                atomicAdd(&acc[2 * A_B2 + h],  cl.z * w);
                atomicAdd(&acc[3 * A_B2 + h],  cl.w * w);
            }
        } else {
            bool dstLo = (R < q);    // R == P -> dst is lo-local
            #pragma unroll 2
            for (int p = lo + tid; p < hi; p += BLK_SORT) {
                unsigned long long t = nt_u64(&tuples[p]);
                unsigned x = (unsigned)t;
                float w = __uint_as_float((unsigned)(t >> 32));
                int l = (int)(x & (A_B2 - 1));
                int h = (int)((x >> AB2_LOG) & (A_B2 - 1));
                int d = dstLo ? l : h;
                int s = dstLo ? h : l;
                float4 c = stg[s];
                atomicAdd(&acc[d],            c.x * w);
                atomicAdd(&acc[A_B2 + d],     c.y * w);
                atomicAdd(&acc[2 * A_B2 + d], c.z * w);
                atomicAdd(&acc[3 * A_B2 + d], c.w * w);
            }
        }
        __syncthreads();
        if (more) {
            stg[tid]            = pre0;
            stg[tid + BLK_SORT] = pre1;
        }
        __syncthreads();
    }
    float4* outp = partials + (size_t)blockIdx.x * A_B2;
    for (int i = tid; i < A_B2; i += BLK_SORT) {
        float4 v = make_float4(acc[i], acc[A_B2 + i],
                               acc[2 * A_B2 + i], acc[3 * A_B2 + i]);
        nt_store_f4(v, &outp[i]);
    }
}

// ---- KC7: reduce nsl partial images -> out ------------------------------
__global__ void kc_final(const float4* __restrict__ partials,
                         float4* __restrict__ out, int n_atoms, int nsl)
{
    int a = blockIdx.x * blockDim.x + threadIdx.x;
    if (a >= n_atoms) return;
    int b = a >> AB2_LOG;
    int local = a & (A_B2 - 1);
    const float4* p = partials + (size_t)(b * nsl) * A_B2 + local;
    float4 r = make_float4(0.f, 0.f, 0.f, 0.f);
    for (int s = 0; s < nsl; ++s) {
        float4 t = p[(size_t)s * A_B2];
        r.x += t.x; r.y += t.y; r.z += t.z; r.w += t.w;
    }
    out[a] = r;
}

// ======================= legacy R5 pipeline (fallback) ===================

__global__ __launch_bounds__(BLOCK) void k_hist(
    const int2* __restrict__ nbr, int* __restrict__ blk_hist,
    int n_edges, int nb)
{
    __shared__ int h[MAXNB];
    for (int i = threadIdx.x; i < nb; i += blockDim.x) h[i] = 0;
    __syncthreads();
    int per = (n_edges + gridDim.x - 1) / gridDim.x;
    int lo = blockIdx.x * per;
    int hi = min(lo + per, n_edges);
    #pragma unroll 4
    for (int e = lo + threadIdx.x; e < hi; e += blockDim.x) {
        unsigned long long v = nt_u64(&nbr[e]);
        int ix = (int)(v & 0xffffffffu);
        int iy = (int)(v >> 32);
        atomicAdd(&h[ix >> AB_LOG], 1);
        atomicAdd(&h[iy >> AB_LOG], 1);
    }
    __syncthreads();
    for (int i = threadIdx.x; i < nb; i += blockDim.x)
        blk_hist[i * NBLK + blockIdx.x] = h[i];
}

__global__ __launch_bounds__(NBLK) void k_rowscan(
    const int* __restrict__ blk_hist, int* __restrict__ offs,
    int* __restrict__ totals)
{
    __shared__ int a[NBLK];
    int b = blockIdx.x, t = threadIdx.x;
    int v = blk_hist[b * NBLK + t];
    a[t] = v;
    __syncthreads();
    for (int off = 1; off < NBLK; off <<= 1) {
        int x = (t >= off) ? a[t - off] : 0;
        __syncthreads();
        a[t] += x;
        __syncthreads();
    }
    offs[b * NBLK + t] = a[t] - v;
    if (t == NBLK - 1) totals[b] = a[t];
}

__global__ __launch_bounds__(MAXNB) void k_bases(
    const int* __restrict__ totals, int* __restrict__ bases, int nb)
{
    __shared__ int a[MAXNB];
    int t = threadIdx.x;
    int v = (t < nb) ? totals[t] : 0;
    a[t] = v;
    __syncthreads();
    for (int off = 1; off < MAXNB; off <<= 1) {
        int x = (t >= off) ? a[t - off] : 0;
        __syncthreads();
        a[t] += x;
        __syncthreads();
    }
    if (t < nb) bases[t] = a[t] - v;
}

__global__ void k_addbase(int* __restrict__ offs, const int* __restrict__ bases, int n)
{
    int i = blockIdx.x * blockDim.x + threadIdx.x;
    if (i < n) offs[i] += bases[i >> NBLK_LG];
}

__global__ __launch_bounds__(BLOCK) void k_scatter(
    const int2* __restrict__ nbr, const float* __restrict__ dist,
    const int* __restrict__ offs, uint2* __restrict__ tuples,
    int n_edges, int nb)
{
    __shared__ int cur[MAXNB];
    for (int i = threadIdx.x; i < nb; i += blockDim.x)
        cur[i] = offs[i * NBLK + blockIdx.x];
    __syncthreads();
    int per = (n_edges + gridDim.x - 1) / gridDim.x;
    int lo = blockIdx.x * per;
    int hi = min(lo + per, n_edges);
    #pragma unroll 2
    for (int e = lo + threadIdx.x; e < hi; e += blockDim.x) {
        unsigned long long v = nt_u64(&nbr[e]);
        int ix = (int)(v & 0xffffffffu);
        int iy = (int)(v >> 32);
        float w = 0.5f / nt_f32(&dist[e]);
        unsigned wb = __float_as_uint(w);
        int pi = atomicAdd(&cur[ix >> AB_LOG], 1);
        tuples[pi] = make_uint2((unsigned)(ix & (A_B - 1)) | ((unsigned)iy << AB_LOG), wb);
        int pj = atomicAdd(&cur[iy >> AB_LOG], 1);
        tuples[pj] = make_uint2((unsigned)(iy & (A_B - 1)) | ((unsigned)ix << AB_LOG), wb);
    }
}

__global__ __launch_bounds__(BLOCK) void k_accum(
    const uint2* __restrict__ tuples, const float4* __restrict__ charges,
    const int* __restrict__ bases, const int* __restrict__ totals,
    float4* __restrict__ partials, int nslice)
{
    __shared__ float acc[4 * PLANE];
    int b = blockIdx.x / nslice;
    int s = blockIdx.x - b * nslice;
    for (int i = threadIdx.x; i < 4 * PLANE; i += BLOCK) acc[i] = 0.f;
    __syncthreads();
    int start = bases[b], cnt = totals[b];
    int lo = start + (int)((long long)cnt * s / nslice);
    int hi = start + (int)((long long)cnt * (s + 1) / nslice);
    const int T = 8;
    int p = lo + threadIdx.x;
    for (; p + (T - 1) * BLOCK < hi; p += T * BLOCK) {
        unsigned long long t[T];
        float4 c[T];
        #pragma unroll
        for (int k = 0; k < T; ++k) t[k] = nt_u64(&tuples[p + k * BLOCK]);
        #pragma unroll
        for (int k = 0; k < T; ++k)
            c[k] = charges[(unsigned)(t[k] & 0xffffffffu) >> AB_LOG];
        #pragma unroll
        for (int k = 0; k < T; ++k) {
            float w = __uint_as_float((unsigned)(t[k] >> 32));
            int d = (int)(t[k] & (A_B - 1));
            atomicAdd(&acc[d],             c[k].x * w);
            atomicAdd(&acc[PLANE + d],     c[k].y * w);
            atomicAdd(&acc[2 * PLANE + d], c[k].z * w);
            atomicAdd(&acc[3 * PLANE + d], c[k].w * w);
        }
    }
    for (; p < hi; p += BLOCK) {
        unsigned long long t = nt_u64(&tuples[p]);
        float4 c = charges[(unsigned)(t & 0xffffffffu) >> AB_LOG];
        float w = __uint_as_float((unsigned)(t >> 32));
        int d = (int)(t & (A_B - 1));
        atomicAdd(&acc[d],             c.x * w);
        atomicAdd(&acc[PLANE + d],     c.y * w);
        atomicAdd(&acc[2 * PLANE + d], c.z * w);
        atomicAdd(&acc[3 * PLANE + d], c.w * w);
    }
    __syncthreads();
    float4* outp = partials + (size_t)blockIdx.x * A_B;
    for (int i = threadIdx.x; i < A_B; i += BLOCK) {
        float4 v = make_float4(acc[i], acc[PLANE + i],
                               acc[2 * PLANE + i], acc[3 * PLANE + i]);
        nt_store_f4(v, &outp[i]);
    }
}

__global__ void k_final(const float4* __restrict__ partials,
                        float4* __restrict__ out, int n_atoms, int nslice)
{
    int a = blockIdx.x * blockDim.x + threadIdx.x;
    if (a >= n_atoms) return;
    int b = a >> AB_LOG;
    int local = a & (A_B - 1);
    const float4* p = partials + (size_t)(b * nslice) * A_B + local;
    float4 r = make_float4(0.f, 0.f, 0.f, 0.f);
    for (int s = 0; s < nslice; ++s) {
        float4 t = p[(size_t)s * A_B];
        r.x += t.x; r.y += t.y; r.z += t.z; r.w += t.w;
    }
    out[a] = r;
}

__global__ __launch_bounds__(BLOCK) void edge_scatter_agent(
    const float4* __restrict__ charges, const int2* __restrict__ nbr,
    const float* __restrict__ dist, float* __restrict__ out, int n_edges)
{
    int e = blockIdx.x * blockDim.x + threadIdx.x;
    if (e >= n_edges) return;
    int2 ij = nbr[e];
    float w = 0.5f / dist[e];
    float4 cj = charges[ij.y];
    float4 ci = charges[ij.x];
    float* oi = out + (size_t)ij.x * 4;
    float* oj = out + (size_t)ij.y * 4;
    atomicAdd(oi + 0, cj.x * w); atomicAdd(oi + 1, cj.y * w);
    atomicAdd(oi + 2, cj.z * w); atomicAdd(oi + 3, cj.w * w);
    atomicAdd(oj + 0, ci.x * w); atomicAdd(oj + 1, ci.y * w);
    atomicAdd(oj + 2, ci.z * w); atomicAdd(oj + 3, ci.w * w);
}

// ============================== launcher =================================

extern "C" void kernel_launch(void* const* d_in, const int* in_sizes, int n_in,
                              void* d_out, int out_size, void* d_ws, size_t ws_size,
                              hipStream_t stream)
{
    const float4* charges = (const float4*)d_in[0];
    const int2*   nbr     = (const int2*)d_in[3];
    const float*  dist    = (const float*)d_in[4];

    int n_edges = in_sizes[4];
    int n_atoms = out_size / 4;

    char* w = (char*)d_ws;
    auto align256 = [](size_t x) { return (x + 255) & ~(size_t)255; };

    // ---- triangular-sort layout ----
    int nb2   = (n_atoms + A_B2 - 1) >> AB2_LOG;       // 98
    int nbins = nb2 * (nb2 + 1) / 2;                   // 4851
    int nsl   = (nb2 + QS_PER - 1) / QS_PER;           // 7

    size_t szT  = (size_t)n_edges * sizeof(uint2);     // 102.4 MB
    size_t szH  = (size_t)NCHUNK * nbins * sizeof(int);
    size_t szP  = (size_t)nb2 * nsl * A_B2 * sizeof(float4);

    size_t off = 0;
    size_t oT  = off; off += align256(szT);
    size_t oCH = off; off += align256(szH);
    size_t oCO = off; off += align256(szH);
    size_t oCT = off; off += align256((size_t)nbins * sizeof(int));
    size_t oCB = off; off += align256((size_t)nbins * sizeof(int));
    size_t oP  = off; off += align256(szP);
    bool tri_ok = (off <= ws_size) && (nbins <= MAXBINS) &&
                  (n_atoms <= (1 << 21)) && (nb2 >= 1);

    if (tri_ok) {
        uint2* tuples = (uint2*)(w + oT);
        int*   chist  = (int*)(w + oCH);
        int*   coffs  = (int*)(w + oCO);
        int*   ctot   = (int*)(w + oCT);
        int*   cbase  = (int*)(w + oCB);
        float4* partials = (float4*)(w + oP);

        kc_hist   <<<NCHUNK, BLK_SORT, 0, stream>>>(nbr, chist, n_edges, nb2, nbins);
        kc_rowscan<<<nbins, NCHUNK, 0, stream>>>(chist, coffs, ctot, nbins);
        kc_bases  <<<1, 1024, 0, stream>>>(ctot, cbase, nbins);
        {
            dim3 g((nbins + 1023) / 1024, NCHUNK);
            kc_addbase<<<g, 1024, 0, stream>>>(coffs, cbase, nbins);
        }
        kc_scatter<<<NCHUNK, BLK_SORT, 0, stream>>>(nbr, dist, coffs, tuples,
                                                    n_edges, nb2, nbins);
        kc_accum  <<<nb2 * nsl, BLK_SORT, 0, stream>>>(tuples, charges, cbase, ctot,
                                                       partials, nb2, nsl, n_atoms);
        kc_final  <<<(n_atoms + 255) / 256, 256, 0, stream>>>(
            partials, (float4*)d_out, n_atoms, nsl);
        return;
    }

    // ---- legacy R5 single-pass layout (fallback) ----
    int nb = (n_atoms + A_B - 1) >> AB_LOG;
    size_t n_pairs = (size_t)2 * n_edges;
    off = 0;
    auto alloc = [&](size_t bytes) -> void* {
        void* p = w + off;
        off += align256(bytes);
        return p;
    };
    uint2* tuples   = (uint2*)alloc(n_pairs * sizeof(uint2));
    int*   blk_hist = (int*)  alloc((size_t)nb * NBLK * sizeof(int));
    int*   offs     = (int*)  alloc((size_t)nb * NBLK * sizeof(int));
    int*   totals   = (int*)  alloc((size_t)nb * sizeof(int));
    int*   bases    = (int*)  alloc((size_t)nb * sizeof(int));
    size_t slice_bytes = (size_t)nb * A_B * 4 * sizeof(float);
    int nslice = 16;
    while (nslice > 1 && off + (size_t)nslice * slice_bytes > ws_size) nslice >>= 1;
    float* partials = (float*)alloc((size_t)nslice * slice_bytes);

    if (off <= ws_size && nb <= MAXNB) {
        k_hist   <<<NBLK, BLOCK, 0, stream>>>(nbr, blk_hist, n_edges, nb);
        k_rowscan<<<nb,   NBLK,  0, stream>>>(blk_hist, offs, totals);
        k_bases  <<<1,    MAXNB, 0, stream>>>(totals, bases, nb);
        k_addbase<<<(nb * NBLK + 255) / 256, 256, 0, stream>>>(offs, bases, nb * NBLK);
        k_scatter<<<NBLK, BLOCK, 0, stream>>>(nbr, dist, offs, tuples, n_edges, nb);
        k_accum  <<<nb * nslice, BLOCK, 0, stream>>>(tuples, charges, bases, totals,
                                                     (float4*)partials, nslice);
        k_final  <<<(n_atoms + 255) / 256, 256, 0, stream>>>(
            (const float4*)partials, (float4*)d_out, n_atoms, nslice);
    } else {
        hipMemsetAsync(d_out, 0, (size_t)out_size * sizeof(float), stream);
        edge_scatter_agent<<<(n_edges + BLOCK - 1) / BLOCK, BLOCK, 0, stream>>>(
            charges, nbr, dist, (float*)d_out, n_edges);
    }
}